// Round 1
// baseline (3020.858 us; speedup 1.0000x reference)
//
#include <hip/hip_runtime.h>
#include <hip/hip_fp16.h>
#include <hip/hip_bf16.h>
#include <stdint.h>

// ---------------------------------------------------------------------------
// ResidualVQ: x (64,512,256) f32, codebooks (6,1024,512) f32
// outputs: quantized_out (64,512,256), indices (64,256,6) as f32,
//          mean_loss, mean_perplexity   -> d_out flat f32, 8486914 elems
// Strategy: residual kept in (NT=16384, D=512) layout.
//   per stage: bf16 MFMA GEMM -> dist' = |c|^2 - 2 r.c  (fp16 matrix + per-row
//   min via atomicMin on ordered-uint key); exact-fp32 refinement over
//   candidates within MARGIN of the min; residual update.
// quantized_out = x - r_final (no separate accumulation).
// ---------------------------------------------------------------------------

#define NTROWS 16384
#define DDIM   512
#define CCODES 1024
#define QSTAGE 6

// ws layout (bytes)
#define OFF_R      ((size_t)0)           // fp32 residual  NT*D*4   = 33554432
#define OFF_RBF    ((size_t)33554432)    // bf16 residual  NT*D*2   = 16777216
#define OFF_CBBF   ((size_t)50331648)    // bf16 codebooks 6*1024*512*2 = 6291456
#define OFF_DIST   ((size_t)56623104)    // fp16 dist      NT*1024*2 = 33554432
#define OFF_MINKEY ((size_t)90177536)    // u32 per-row min key, NT*4
#define OFF_IDX    ((size_t)90243072)    // i32 chosen idx, NT*4
#define OFF_CBSQ   ((size_t)90308608)    // f32 |c|^2, 6*1024*4
#define OFF_HIST   ((size_t)90333184)    // u32 hist, 6*1024*4
#define OFF_LOSS   ((size_t)90357760)    // f32 loss sums, 8*4

#define OUT_IDX_OFF  ((size_t)8388608)
#define OUT_SCAL_OFF ((size_t)8486912)

typedef __attribute__((ext_vector_type(8))) short short8;
typedef __attribute__((ext_vector_type(4))) float f32x4;

__device__ __forceinline__ unsigned short f2bf(float f) {
    uint32_t u = __float_as_uint(f);
    uint32_t r = (u + 0x7fffu + ((u >> 16) & 1u)) >> 16;   // RNE
    return (unsigned short)r;
}
__device__ __forceinline__ uint32_t fkey(float f) {        // order-preserving f32->u32
    uint32_t u = __float_as_uint(f);
    return (u & 0x80000000u) ? ~u : (u | 0x80000000u);
}
__device__ __forceinline__ float funkey(uint32_t k) {
    uint32_t u = (k & 0x80000000u) ? (k ^ 0x80000000u) : ~k;
    return __uint_as_float(u);
}
__device__ __forceinline__ float wave_sum(float v) {
    for (int m = 32; m; m >>= 1) v += __shfl_xor(v, m, 64);
    return v;
}
__device__ __forceinline__ void async_load16(const void* g, void* l) {
    __builtin_amdgcn_global_load_lds(
        (__attribute__((address_space(1))) void*)(void*)g,
        (__attribute__((address_space(3))) void*)l, 16, 0, 0);
}

// --------------------------------------------------------------------------
// prep_cb: bf16 codebooks + |c|^2 ; also zero hist/loss (block 0)
// grid 1536 x 256 (wave per code row)
// --------------------------------------------------------------------------
__global__ __launch_bounds__(256) void prep_cb_kernel(
    const float* __restrict__ cb, unsigned short* __restrict__ cbbf,
    float* __restrict__ cbsq, unsigned int* __restrict__ hist,
    float* __restrict__ loss)
{
    const int wave = threadIdx.x >> 6, lane = threadIdx.x & 63;
    const int row = blockIdx.x * 4 + wave;            // 0..6143
    const float* p = cb + (size_t)row * DDIM;
    unsigned short* pb = cbbf + (size_t)row * DDIM;
    float s = 0.f;
#pragma unroll
    for (int t = 0; t < 8; ++t) {
        float v = p[lane + 64 * t];
        pb[lane + 64 * t] = f2bf(v);
        s += v * v;
    }
    s = wave_sum(s);
    if (lane == 0) cbsq[row] = s;
    if (blockIdx.x == 0) {
        for (int i = threadIdx.x; i < QSTAGE * CCODES; i += 256) hist[i] = 0u;
        if (threadIdx.x < 8) loss[threadIdx.x] = 0.f;
    }
}

// --------------------------------------------------------------------------
// prep_x: transpose x (N,D,T) -> r (NT,D) fp32+bf16 ; init minkey
// grid (16,8,64) block (32,8)
// --------------------------------------------------------------------------
__global__ void prep_x_kernel(const float* __restrict__ x, float* __restrict__ r,
                              unsigned short* __restrict__ rbf,
                              unsigned int* __restrict__ minkey)
{
    __shared__ float tile[32][33];
    const int d0 = blockIdx.x * 32, t0 = blockIdx.y * 32, n = blockIdx.z;
    const int tx = threadIdx.x, ty = threadIdx.y;
    const float* xp = x + (size_t)n * (DDIM * 256);
#pragma unroll
    for (int s = 0; s < 4; ++s) {
        int dd = ty + s * 8;
        tile[dd][tx] = xp[(size_t)(d0 + dd) * 256 + t0 + tx];
    }
    __syncthreads();
#pragma unroll
    for (int s = 0; s < 4; ++s) {
        int tt = ty + s * 8;
        float v = tile[tx][tt];
        size_t off = (size_t)(n * 256 + t0 + tt) * DDIM + d0 + tx;
        r[off] = v;
        rbf[off] = f2bf(v);
    }
    if (blockIdx.x == 0 && ty == 0) minkey[n * 256 + t0 + tx] = 0xFFFFFFFFu;
}

// --------------------------------------------------------------------------
// GEMM: dist'[row][col] = cbsq[col] - 2 * dot(r_row, c_col), bf16 MFMA
// m97-style: 128x128 tile, BK=32, global_load_lds w16, 16x16x32 mfma
// grid (8,128) x 256
// --------------------------------------------------------------------------
__global__ __launch_bounds__(256) void gemm_dist_kernel(
    const unsigned short* __restrict__ Abf,   // NT x 512 bf16
    const unsigned short* __restrict__ Bbf,   // 1024 x 512 bf16 (stage slice)
    const float* __restrict__ cbsq,           // 1024 (stage slice)
    _Float16* __restrict__ dist,              // NT x 1024
    unsigned int* __restrict__ minkey)        // NT
{
    __shared__ __align__(16) unsigned short lA[128 * 32];
    __shared__ __align__(16) unsigned short lB[128 * 32];
    const int tid = threadIdx.x;
    const int wave = tid >> 6, lane = tid & 63;
    const int quad = lane >> 4, l15 = lane & 15;
    const int tm = blockIdx.y, tn = blockIdx.x;
    const int wm = wave & 1, wn = wave >> 1;

    f32x4 acc[4][4];
#pragma unroll
    for (int i = 0; i < 4; ++i)
#pragma unroll
        for (int j = 0; j < 4; ++j) acc[i][j] = (f32x4){0.f, 0.f, 0.f, 0.f};

    // staging: wave w loads rows [w*16 + lane>>2] and +64, chunk = lane&3 (16B)
    const int srow = wave * 16 + (lane >> 2);
    const int schunk = lane & 3;
    const unsigned short* gA0 = Abf + (size_t)(tm * 128 + srow) * DDIM + schunk * 8;
    const unsigned short* gA1 = gA0 + 64 * DDIM;
    const unsigned short* gB0 = Bbf + (size_t)(tn * 128 + srow) * DDIM + schunk * 8;
    const unsigned short* gB1 = gB0 + 64 * DDIM;
    unsigned short* sA0 = &lA[srow * 32 + schunk * 8];
    unsigned short* sA1 = &lA[(64 + srow) * 32 + schunk * 8];
    unsigned short* sB0 = &lB[srow * 32 + schunk * 8];
    unsigned short* sB1 = &lB[(64 + srow) * 32 + schunk * 8];

    for (int kt = 0; kt < DDIM / 32; ++kt) {
        async_load16(gA0, sA0); async_load16(gA1, sA1);
        async_load16(gB0, sB0); async_load16(gB1, sB1);
        gA0 += 32; gA1 += 32; gB0 += 32; gB1 += 32;
        __syncthreads();   // drains vmcnt before LDS reads
        short8 af[4], bfr[4];
#pragma unroll
        for (int i = 0; i < 4; ++i)
            af[i] = *(const short8*)&lA[(wm * 64 + i * 16 + l15) * 32 + quad * 8];
#pragma unroll
        for (int j = 0; j < 4; ++j)
            bfr[j] = *(const short8*)&lB[(wn * 64 + j * 16 + l15) * 32 + quad * 8];
#pragma unroll
        for (int i = 0; i < 4; ++i)
#pragma unroll
            for (int j = 0; j < 4; ++j)
                acc[i][j] = __builtin_amdgcn_mfma_f32_16x16x32_bf16(
                    af[i], bfr[j], acc[i][j], 0, 0, 0);
        __syncthreads();   // before next tile overwrites LDS
    }

    // epilogue: C/D layout col=lane&15, row=quad*4+reg  (m89-verified)
    const int rowbase = tm * 128 + wm * 64 + quad * 4;
    const int colbase = tn * 128 + wn * 64 + l15;
    float cbs[4];
#pragma unroll
    for (int j = 0; j < 4; ++j) cbs[j] = cbsq[colbase + j * 16];
#pragma unroll
    for (int i = 0; i < 4; ++i) {
#pragma unroll
        for (int reg = 0; reg < 4; ++reg) {
            const int row = rowbase + i * 16 + reg;
            float dmin = 1e30f;
#pragma unroll
            for (int j = 0; j < 4; ++j) {
                float dv = cbs[j] - 2.0f * acc[i][j][reg];
                dist[(size_t)row * CCODES + colbase + j * 16] = (_Float16)dv;
                dmin = fminf(dmin, dv);
            }
            for (int m = 8; m; m >>= 1) dmin = fminf(dmin, __shfl_xor(dmin, m, 64));
            if (l15 == 0) atomicMin(&minkey[row], fkey(dmin));
        }
    }
}

// --------------------------------------------------------------------------
// refine: per row, candidates within MARGIN of bf16-min -> exact fp32 argmin
// grid 4096 x 256 (wave per row)
// --------------------------------------------------------------------------
#define MARGIN 8.0f
__global__ __launch_bounds__(256) void refine_kernel(
    const float* __restrict__ r, const float* __restrict__ cbq,
    const float* __restrict__ cbsqq, const _Float16* __restrict__ dist,
    unsigned int* __restrict__ minkey, int* __restrict__ idx_ws,
    float* __restrict__ out_idx, unsigned int* __restrict__ histq, int q)
{
    const int wave = threadIdx.x >> 6, lane = threadIdx.x & 63;
    const int nt = blockIdx.x * 4 + wave;
    const float* rrow = r + (size_t)nt * DDIM;
    float s = 0.f;
#pragma unroll
    for (int t = 0; t < 8; ++t) { float v = rrow[lane + 64 * t]; s += v * v; }
    const float sumx = wave_sum(s);

    const unsigned int k = minkey[nt];
    if (lane == 0) minkey[nt] = 0xFFFFFFFFu;   // reset for next stage
    const float thr = funkey(k) + MARGIN;

    float best = 1e30f;
    int bestc = 0;
    const _Float16* drow = dist + (size_t)nt * CCODES;
    for (int sg = 0; sg < 16; ++sg) {
        const int c = sg * 64 + lane;
        const float dh = (float)drow[c];
        unsigned long long mask = __ballot(dh <= thr);
        while (mask) {
            const int src = __ffsll((unsigned long long)mask) - 1;
            mask &= mask - 1;
            const int cc = __shfl(c, src, 64);
            const float* crow = cbq + (size_t)cc * DDIM;
            float dot = 0.f;
#pragma unroll
            for (int t = 0; t < 8; ++t)
                dot += rrow[lane + 64 * t] * crow[lane + 64 * t];
            dot = wave_sum(dot);
            const float de = (sumx - 2.0f * dot) + cbsqq[cc];
            if (de < best) { best = de; bestc = cc; }   // ascending cc => first-idx tiebreak
        }
    }
    if (lane == 0) {
        idx_ws[nt] = bestc;
        out_idx[(size_t)nt * QSTAGE + q] = (float)bestc;
        atomicAdd(&histq[bestc], 1u);
    }
}

// --------------------------------------------------------------------------
// update: r -= cb[idx]; write bf16; accumulate commit loss = sum(r_new^2)
// grid 8192 x 256 (thread = 4 contiguous d of one row)
// --------------------------------------------------------------------------
__global__ __launch_bounds__(256) void update_kernel(
    float* __restrict__ r, unsigned short* __restrict__ rbf,
    const float* __restrict__ cbq, const int* __restrict__ idx_ws,
    float* __restrict__ lossq, int write_bf)
{
    const int gid = blockIdx.x * 256 + threadIdx.x;
    const int row = gid >> 7;
    const int d4 = (gid & 127) << 2;
    const int idx = idx_ws[row];
    float4 rv = *(const float4*)(r + (size_t)row * DDIM + d4);
    float4 cv = *(const float4*)(cbq + (size_t)idx * DDIM + d4);
    float4 nv = make_float4(rv.x - cv.x, rv.y - cv.y, rv.z - cv.z, rv.w - cv.w);
    *(float4*)(r + (size_t)row * DDIM + d4) = nv;
    if (write_bf) {
        ushort4 b = make_ushort4(f2bf(nv.x), f2bf(nv.y), f2bf(nv.z), f2bf(nv.w));
        *(ushort4*)(rbf + (size_t)row * DDIM + d4) = b;
    }
    float sq = nv.x * nv.x + nv.y * nv.y + nv.z * nv.z + nv.w * nv.w;
    sq = wave_sum(sq);
    if ((threadIdx.x & 63) == 0) atomicAdd(lossq, sq);
}

// --------------------------------------------------------------------------
// final: out = x - r_final, transposed back to (N,D,T)
// grid (16,8,64) block (32,8)
// --------------------------------------------------------------------------
__global__ void final_out_kernel(const float* __restrict__ x,
                                 const float* __restrict__ r,
                                 float* __restrict__ out)
{
    __shared__ float tile[32][33];    // [t'][d']
    const int d0 = blockIdx.x * 32, t0 = blockIdx.y * 32, n = blockIdx.z;
    const int tx = threadIdx.x, ty = threadIdx.y;
#pragma unroll
    for (int s = 0; s < 4; ++s) {
        int tt = ty + s * 8;
        tile[tt][tx] = r[(size_t)(n * 256 + t0 + tt) * DDIM + d0 + tx];
    }
    __syncthreads();
    const float* xp = x + (size_t)n * (DDIM * 256);
    float* op = out + (size_t)n * (DDIM * 256);
#pragma unroll
    for (int s = 0; s < 4; ++s) {
        int dd = ty + s * 8;
        size_t off = (size_t)(d0 + dd) * 256 + t0 + tx;
        op[off] = xp[off] - tile[tx][dd];
    }
}

// --------------------------------------------------------------------------
// scalars: mean commit loss + mean perplexity
// --------------------------------------------------------------------------
__global__ __launch_bounds__(256) void scalars_kernel(
    const unsigned int* __restrict__ hist, const float* __restrict__ loss,
    float* __restrict__ out2)
{
    __shared__ float red[4];
    __shared__ float perp_acc;
    const int tid = threadIdx.x, wave = tid >> 6, lane = tid & 63;
    if (tid == 0) perp_acc = 0.f;
    __syncthreads();
    for (int q = 0; q < QSTAGE; ++q) {
        float s = 0.f;
        for (int c = tid; c < CCODES; c += 256) {
            float p = (float)hist[q * CCODES + c] * (1.0f / (float)NTROWS);
            s += p * logf(p + 1e-10f);
        }
        s = wave_sum(s);
        if (lane == 0) red[wave] = s;
        __syncthreads();
        if (tid == 0) {
            float tot = red[0] + red[1] + red[2] + red[3];
            perp_acc += expf(-tot);
        }
        __syncthreads();
    }
    if (tid == 0) {
        float lsum = 0.f;
        for (int q = 0; q < QSTAGE; ++q) lsum += loss[q];
        out2[0] = (lsum / (float)QSTAGE) / ((float)NTROWS * (float)DDIM);
        out2[1] = perp_acc / (float)QSTAGE;
    }
}

// --------------------------------------------------------------------------
extern "C" void kernel_launch(void* const* d_in, const int* in_sizes, int n_in,
                              void* d_out, int out_size, void* d_ws, size_t ws_size,
                              hipStream_t stream)
{
    const float* x  = (const float*)d_in[0];
    const float* cb = (const float*)d_in[1];
    float* out = (float*)d_out;
    char* ws = (char*)d_ws;

    float*          r      = (float*)(ws + OFF_R);
    unsigned short* rbf    = (unsigned short*)(ws + OFF_RBF);
    unsigned short* cbbf   = (unsigned short*)(ws + OFF_CBBF);
    _Float16*       dist   = (_Float16*)(ws + OFF_DIST);
    unsigned int*   minkey = (unsigned int*)(ws + OFF_MINKEY);
    int*            idxws  = (int*)(ws + OFF_IDX);
    float*          cbsq   = (float*)(ws + OFF_CBSQ);
    unsigned int*   hist   = (unsigned int*)(ws + OFF_HIST);
    float*          loss   = (float*)(ws + OFF_LOSS);

    prep_cb_kernel<<<1536, 256, 0, stream>>>(cb, cbbf, cbsq, hist, loss);
    prep_x_kernel<<<dim3(16, 8, 64), dim3(32, 8), 0, stream>>>(x, r, rbf, minkey);

    for (int q = 0; q < QSTAGE; ++q) {
        const size_t cboff = (size_t)q * CCODES * DDIM;
        gemm_dist_kernel<<<dim3(8, 128), 256, 0, stream>>>(
            rbf, cbbf + cboff, cbsq + q * CCODES, dist, minkey);
        refine_kernel<<<4096, 256, 0, stream>>>(
            r, cb + cboff, cbsq + q * CCODES, dist, minkey, idxws,
            out + OUT_IDX_OFF, hist + q * CCODES, q);
        update_kernel<<<8192, 256, 0, stream>>>(
            r, rbf, cb + cboff, idxws, loss + q, (q < QSTAGE - 1) ? 1 : 0);
    }

    final_out_kernel<<<dim3(16, 8, 64), dim3(32, 8), 0, stream>>>(x, r, out);
    scalars_kernel<<<1, 256, 0, stream>>>(hist, loss, out + OUT_SCAL_OFF);
}

// Round 2
// 621.471 us; speedup vs baseline: 4.8608x; 4.8608x over previous
//
#include <hip/hip_runtime.h>
#include <hip/hip_fp16.h>
#include <hip/hip_bf16.h>
#include <stdint.h>

// ---------------------------------------------------------------------------
// ResidualVQ: x (64,512,256) f32, codebooks (6,1024,512) f32
// outputs: quantized_out (64,512,256), indices (64,256,6) as f32,
//          mean_loss, mean_perplexity   -> d_out flat f32, 8486914 elems
//
// R1 -> R2: update_kernel removed (was 84% of runtime: 32768 same-address
// fp32 atomicAdds serialize at ~12ns each = 420us/launch). Residual update
// merged into refine_kernel (bestc is wave-uniform; r row already in regs).
// Commit loss = sum of per-row best distance (identical to sum(r_new^2)),
// accumulated via 256-bin atomics (64 adds/bin) instead of one address.
// ---------------------------------------------------------------------------

#define NTROWS 16384
#define DDIM   512
#define CCODES 1024
#define QSTAGE 6

// ws layout (bytes)
#define OFF_R      ((size_t)0)           // fp32 residual  NT*D*4   = 33554432
#define OFF_RBF    ((size_t)33554432)    // bf16 residual  NT*D*2   = 16777216
#define OFF_CBBF   ((size_t)50331648)    // bf16 codebooks 6*1024*512*2 = 6291456
#define OFF_DIST   ((size_t)56623104)    // fp16 dist      NT*1024*2 = 33554432
#define OFF_MINKEY ((size_t)90177536)    // u32 per-row min key, NT*4
#define OFF_CBSQ   ((size_t)90243072)    // f32 |c|^2, 6*1024*4
#define OFF_HIST   ((size_t)90267648)    // u32 hist, 6*1024*4
#define OFF_LOSS   ((size_t)90292224)    // f32 loss bins, 6*256*4 = 6144
#define WS_END     ((size_t)90298368)

#define OUT_IDX_OFF  ((size_t)8388608)
#define OUT_SCAL_OFF ((size_t)8486912)

typedef __attribute__((ext_vector_type(8))) short short8;
typedef __attribute__((ext_vector_type(4))) float f32x4;

__device__ __forceinline__ unsigned short f2bf(float f) {
    uint32_t u = __float_as_uint(f);
    uint32_t r = (u + 0x7fffu + ((u >> 16) & 1u)) >> 16;   // RNE
    return (unsigned short)r;
}
__device__ __forceinline__ uint32_t fkey(float f) {        // order-preserving f32->u32
    uint32_t u = __float_as_uint(f);
    return (u & 0x80000000u) ? ~u : (u | 0x80000000u);
}
__device__ __forceinline__ float funkey(uint32_t k) {
    uint32_t u = (k & 0x80000000u) ? (k ^ 0x80000000u) : ~k;
    return __uint_as_float(u);
}
__device__ __forceinline__ float wave_sum(float v) {
    for (int m = 32; m; m >>= 1) v += __shfl_xor(v, m, 64);
    return v;
}
__device__ __forceinline__ void async_load16(const void* g, void* l) {
    __builtin_amdgcn_global_load_lds(
        (__attribute__((address_space(1))) void*)(void*)g,
        (__attribute__((address_space(3))) void*)l, 16, 0, 0);
}

// --------------------------------------------------------------------------
// prep_cb: bf16 codebooks + |c|^2 ; also zero hist/loss bins (block 0)
// grid 1536 x 256 (wave per code row)
// --------------------------------------------------------------------------
__global__ __launch_bounds__(256) void prep_cb_kernel(
    const float* __restrict__ cb, unsigned short* __restrict__ cbbf,
    float* __restrict__ cbsq, unsigned int* __restrict__ hist,
    float* __restrict__ loss_bins)
{
    const int wave = threadIdx.x >> 6, lane = threadIdx.x & 63;
    const int row = blockIdx.x * 4 + wave;            // 0..6143
    const float* p = cb + (size_t)row * DDIM;
    unsigned short* pb = cbbf + (size_t)row * DDIM;
    float s = 0.f;
#pragma unroll
    for (int t = 0; t < 8; ++t) {
        float v = p[lane + 64 * t];
        pb[lane + 64 * t] = f2bf(v);
        s += v * v;
    }
    s = wave_sum(s);
    if (lane == 0) cbsq[row] = s;
    if (blockIdx.x == 0) {
        for (int i = threadIdx.x; i < QSTAGE * CCODES; i += 256) hist[i] = 0u;
        for (int i = threadIdx.x; i < QSTAGE * 256; i += 256) loss_bins[i] = 0.f;
    }
}

// --------------------------------------------------------------------------
// prep_x: transpose x (N,D,T) -> r (NT,D) fp32+bf16 ; init minkey
// grid (16,8,64) block (32,8)
// --------------------------------------------------------------------------
__global__ void prep_x_kernel(const float* __restrict__ x, float* __restrict__ r,
                              unsigned short* __restrict__ rbf,
                              unsigned int* __restrict__ minkey)
{
    __shared__ float tile[32][33];
    const int d0 = blockIdx.x * 32, t0 = blockIdx.y * 32, n = blockIdx.z;
    const int tx = threadIdx.x, ty = threadIdx.y;
    const float* xp = x + (size_t)n * (DDIM * 256);
#pragma unroll
    for (int s = 0; s < 4; ++s) {
        int dd = ty + s * 8;
        tile[dd][tx] = xp[(size_t)(d0 + dd) * 256 + t0 + tx];
    }
    __syncthreads();
#pragma unroll
    for (int s = 0; s < 4; ++s) {
        int tt = ty + s * 8;
        float v = tile[tx][tt];
        size_t off = (size_t)(n * 256 + t0 + tt) * DDIM + d0 + tx;
        r[off] = v;
        rbf[off] = f2bf(v);
    }
    if (blockIdx.x == 0 && ty == 0) minkey[n * 256 + t0 + tx] = 0xFFFFFFFFu;
}

// --------------------------------------------------------------------------
// GEMM: dist'[row][col] = cbsq[col] - 2 * dot(r_row, c_col), bf16 MFMA
// m97-style: 128x128 tile, BK=32, global_load_lds w16, 16x16x32 mfma
// grid (8,128) x 256
// --------------------------------------------------------------------------
__global__ __launch_bounds__(256) void gemm_dist_kernel(
    const unsigned short* __restrict__ Abf,   // NT x 512 bf16
    const unsigned short* __restrict__ Bbf,   // 1024 x 512 bf16 (stage slice)
    const float* __restrict__ cbsq,           // 1024 (stage slice)
    _Float16* __restrict__ dist,              // NT x 1024
    unsigned int* __restrict__ minkey)        // NT
{
    __shared__ __align__(16) unsigned short lA[128 * 32];
    __shared__ __align__(16) unsigned short lB[128 * 32];
    const int tid = threadIdx.x;
    const int wave = tid >> 6, lane = tid & 63;
    const int quad = lane >> 4, l15 = lane & 15;
    const int tm = blockIdx.y, tn = blockIdx.x;
    const int wm = wave & 1, wn = wave >> 1;

    f32x4 acc[4][4];
#pragma unroll
    for (int i = 0; i < 4; ++i)
#pragma unroll
        for (int j = 0; j < 4; ++j) acc[i][j] = (f32x4){0.f, 0.f, 0.f, 0.f};

    // staging: wave w loads rows [w*16 + lane>>2] and +64, chunk = lane&3 (16B)
    const int srow = wave * 16 + (lane >> 2);
    const int schunk = lane & 3;
    const unsigned short* gA0 = Abf + (size_t)(tm * 128 + srow) * DDIM + schunk * 8;
    const unsigned short* gA1 = gA0 + 64 * DDIM;
    const unsigned short* gB0 = Bbf + (size_t)(tn * 128 + srow) * DDIM + schunk * 8;
    const unsigned short* gB1 = gB0 + 64 * DDIM;
    unsigned short* sA0 = &lA[srow * 32 + schunk * 8];
    unsigned short* sA1 = &lA[(64 + srow) * 32 + schunk * 8];
    unsigned short* sB0 = &lB[srow * 32 + schunk * 8];
    unsigned short* sB1 = &lB[(64 + srow) * 32 + schunk * 8];

    for (int kt = 0; kt < DDIM / 32; ++kt) {
        async_load16(gA0, sA0); async_load16(gA1, sA1);
        async_load16(gB0, sB0); async_load16(gB1, sB1);
        gA0 += 32; gA1 += 32; gB0 += 32; gB1 += 32;
        __syncthreads();   // drains vmcnt before LDS reads
        short8 af[4], bfr[4];
#pragma unroll
        for (int i = 0; i < 4; ++i)
            af[i] = *(const short8*)&lA[(wm * 64 + i * 16 + l15) * 32 + quad * 8];
#pragma unroll
        for (int j = 0; j < 4; ++j)
            bfr[j] = *(const short8*)&lB[(wn * 64 + j * 16 + l15) * 32 + quad * 8];
#pragma unroll
        for (int i = 0; i < 4; ++i)
#pragma unroll
            for (int j = 0; j < 4; ++j)
                acc[i][j] = __builtin_amdgcn_mfma_f32_16x16x32_bf16(
                    af[i], bfr[j], acc[i][j], 0, 0, 0);
        __syncthreads();   // before next tile overwrites LDS
    }

    // epilogue: C/D layout col=lane&15, row=quad*4+reg  (m89-verified)
    const int rowbase = tm * 128 + wm * 64 + quad * 4;
    const int colbase = tn * 128 + wn * 64 + l15;
    float cbs[4];
#pragma unroll
    for (int j = 0; j < 4; ++j) cbs[j] = cbsq[colbase + j * 16];
#pragma unroll
    for (int i = 0; i < 4; ++i) {
#pragma unroll
        for (int reg = 0; reg < 4; ++reg) {
            const int row = rowbase + i * 16 + reg;
            float dmin = 1e30f;
#pragma unroll
            for (int j = 0; j < 4; ++j) {
                float dv = cbs[j] - 2.0f * acc[i][j][reg];
                dist[(size_t)row * CCODES + colbase + j * 16] = (_Float16)dv;
                dmin = fminf(dmin, dv);
            }
            for (int m = 8; m; m >>= 1) dmin = fminf(dmin, __shfl_xor(dmin, m, 64));
            if (l15 == 0) atomicMin(&minkey[row], fkey(dmin));
        }
    }
}

// --------------------------------------------------------------------------
// refine+update: per row, candidates within MARGIN of bf16-min -> exact fp32
// argmin; then r -= cb[best] (bestc is wave-uniform), write fp32+bf16,
// loss += best (256-bin atomics).
// grid 4096 x 256 (wave per row)
// --------------------------------------------------------------------------
#define MARGIN 8.0f
__global__ __launch_bounds__(256) void refine_kernel(
    float* __restrict__ r, unsigned short* __restrict__ rbf,
    const float* __restrict__ cbq, const float* __restrict__ cbsqq,
    const _Float16* __restrict__ dist, unsigned int* __restrict__ minkey,
    float* __restrict__ out_idx, unsigned int* __restrict__ histq,
    float* __restrict__ loss_bins, int q, int write_bf)
{
    const int wave = threadIdx.x >> 6, lane = threadIdx.x & 63;
    const int nt = blockIdx.x * 4 + wave;
    float* rrow = r + (size_t)nt * DDIM;
    float rv[8];
    float s = 0.f;
#pragma unroll
    for (int t = 0; t < 8; ++t) { rv[t] = rrow[lane + 64 * t]; s += rv[t] * rv[t]; }
    const float sumx = wave_sum(s);

    const unsigned int k = minkey[nt];
    if (lane == 0) minkey[nt] = 0xFFFFFFFFu;   // reset for next stage
    const float thr = funkey(k) + MARGIN;

    float best = 1e30f;
    int bestc = 0;
    const _Float16* drow = dist + (size_t)nt * CCODES;
    for (int sg = 0; sg < 16; ++sg) {
        const int c = sg * 64 + lane;
        const float dh = (float)drow[c];
        unsigned long long mask = __ballot(dh <= thr);
        while (mask) {
            const int src = __ffsll((unsigned long long)mask) - 1;
            mask &= mask - 1;
            const int cc = __shfl(c, src, 64);
            const float* crow = cbq + (size_t)cc * DDIM;
            float dot = 0.f;
#pragma unroll
            for (int t = 0; t < 8; ++t)
                dot += rv[t] * crow[lane + 64 * t];
            dot = wave_sum(dot);
            const float de = (sumx - 2.0f * dot) + cbsqq[cc];
            if (de < best) { best = de; bestc = cc; }   // ascending cc => first-idx tiebreak
        }
    }

    // merged residual update: bestc/best are wave-uniform
    const float* cbest = cbq + (size_t)bestc * DDIM;
#pragma unroll
    for (int t = 0; t < 8; ++t) {
        const float nv = rv[t] - cbest[lane + 64 * t];
        rrow[lane + 64 * t] = nv;
        if (write_bf) rbf[(size_t)nt * DDIM + lane + 64 * t] = f2bf(nv);
    }

    if (lane == 0) {
        out_idx[(size_t)nt * QSTAGE + q] = (float)bestc;
        atomicAdd(&histq[bestc], 1u);
        atomicAdd(&loss_bins[q * 256 + (blockIdx.x & 255)], best);
    }
}

// --------------------------------------------------------------------------
// final: out = x - r_final, transposed back to (N,D,T)
// grid (16,8,64) block (32,8)
// --------------------------------------------------------------------------
__global__ void final_out_kernel(const float* __restrict__ x,
                                 const float* __restrict__ r,
                                 float* __restrict__ out)
{
    __shared__ float tile[32][33];    // [t'][d']
    const int d0 = blockIdx.x * 32, t0 = blockIdx.y * 32, n = blockIdx.z;
    const int tx = threadIdx.x, ty = threadIdx.y;
#pragma unroll
    for (int s = 0; s < 4; ++s) {
        int tt = ty + s * 8;
        tile[tt][tx] = r[(size_t)(n * 256 + t0 + tt) * DDIM + d0 + tx];
    }
    __syncthreads();
    const float* xp = x + (size_t)n * (DDIM * 256);
    float* op = out + (size_t)n * (DDIM * 256);
#pragma unroll
    for (int s = 0; s < 4; ++s) {
        int dd = ty + s * 8;
        size_t off = (size_t)(d0 + dd) * 256 + t0 + tx;
        op[off] = xp[off] - tile[tx][dd];
    }
}

// --------------------------------------------------------------------------
// scalars: mean commit loss + mean perplexity
// --------------------------------------------------------------------------
__global__ __launch_bounds__(256) void scalars_kernel(
    const unsigned int* __restrict__ hist, const float* __restrict__ loss_bins,
    float* __restrict__ out2)
{
    __shared__ float red[4];
    __shared__ float perp_acc;
    const int tid = threadIdx.x, wave = tid >> 6, lane = tid & 63;
    if (tid == 0) perp_acc = 0.f;
    __syncthreads();
    for (int q = 0; q < QSTAGE; ++q) {
        float s = 0.f;
        for (int c = tid; c < CCODES; c += 256) {
            float p = (float)hist[q * CCODES + c] * (1.0f / (float)NTROWS);
            s += p * logf(p + 1e-10f);
        }
        s = wave_sum(s);
        if (lane == 0) red[wave] = s;
        __syncthreads();
        if (tid == 0) {
            float tot = red[0] + red[1] + red[2] + red[3];
            perp_acc += expf(-tot);
        }
        __syncthreads();
    }
    if (tid == 0) {
        float lsum = 0.f;
        for (int q = 0; q < QSTAGE; ++q)
            for (int b = 0; b < 256; ++b) lsum += loss_bins[q * 256 + b];
        out2[0] = (lsum / (float)QSTAGE) / ((float)NTROWS * (float)DDIM);
        out2[1] = perp_acc / (float)QSTAGE;
    }
}

// --------------------------------------------------------------------------
extern "C" void kernel_launch(void* const* d_in, const int* in_sizes, int n_in,
                              void* d_out, int out_size, void* d_ws, size_t ws_size,
                              hipStream_t stream)
{
    const float* x  = (const float*)d_in[0];
    const float* cb = (const float*)d_in[1];
    float* out = (float*)d_out;
    char* ws = (char*)d_ws;

    float*          r      = (float*)(ws + OFF_R);
    unsigned short* rbf    = (unsigned short*)(ws + OFF_RBF);
    unsigned short* cbbf   = (unsigned short*)(ws + OFF_CBBF);
    _Float16*       dist   = (_Float16*)(ws + OFF_DIST);
    unsigned int*   minkey = (unsigned int*)(ws + OFF_MINKEY);
    float*          cbsq   = (float*)(ws + OFF_CBSQ);
    unsigned int*   hist   = (unsigned int*)(ws + OFF_HIST);
    float*          lbins  = (float*)(ws + OFF_LOSS);

    prep_cb_kernel<<<1536, 256, 0, stream>>>(cb, cbbf, cbsq, hist, lbins);
    prep_x_kernel<<<dim3(16, 8, 64), dim3(32, 8), 0, stream>>>(x, r, rbf, minkey);

    for (int q = 0; q < QSTAGE; ++q) {
        const size_t cboff = (size_t)q * CCODES * DDIM;
        gemm_dist_kernel<<<dim3(8, 128), 256, 0, stream>>>(
            rbf, cbbf + cboff, cbsq + q * CCODES, dist, minkey);
        refine_kernel<<<4096, 256, 0, stream>>>(
            r, rbf, cb + cboff, cbsq + q * CCODES, dist, minkey,
            out + OUT_IDX_OFF, hist + q * CCODES, lbins,
            q, (q < QSTAGE - 1) ? 1 : 0);
    }

    final_out_kernel<<<dim3(16, 8, 64), dim3(32, 8), 0, stream>>>(x, r, out);
    scalars_kernel<<<1, 256, 0, stream>>>(hist, lbins, out + OUT_SCAL_OFF);
}